// Round 1
// baseline (173.281 us; speedup 1.0000x reference)
//
#include <hip/hip_runtime.h>
#include <hip/hip_bf16.h>

#define HEADS 8
#define DK 32
#define DV 64
#define DIM 256
#define NCTX 1024
#define NB 8
#define IDK 256
#define IDV 512
#define SCALE 0.17677669529663687f
#define INV_SCALE 5.656854249492381f
#define BN_EPS 1e-5f

typedef __bf16 bf16x8 __attribute__((ext_vector_type(8)));
typedef float f32x4 __attribute__((ext_vector_type(4)));

// ---------------- transpose x[b,c,n] f32 -> xT[b,n,c] bf16 ----------------
__global__ __launch_bounds__(256) void k_transpose(const float* __restrict__ x,
                                                   __bf16* __restrict__ xT) {
  __shared__ float t[64][65];
  int b = blockIdx.z, c0 = blockIdx.y * 64, n0 = blockIdx.x * 64;
  int col = threadIdx.x & 63, rb = threadIdx.x >> 6;
  const float* xp = x + ((size_t)b * DIM + c0) * NCTX + n0;
#pragma unroll
  for (int r = 0; r < 16; ++r) {
    int row = rb + 4 * r;
    t[row][col] = xp[(size_t)row * NCTX + col];
  }
  __syncthreads();
  __bf16* op = xT + ((size_t)b * NCTX + n0) * DIM + c0;
#pragma unroll
  for (int r = 0; r < 16; ++r) {
    int i = rb + 4 * r;
    op[(size_t)i * DIM + col] = (__bf16)t[col][i];
  }
}

// ---------------- Q/K projection: A=xT (M=i), B=W (N=o), K=c=256 ----------------
// writes Q,K as [b,h,n,dk] bf16, BN folded (+SCALE folded into Q)
__global__ __launch_bounds__(256) void k_proj_qk(
    const __bf16* __restrict__ xT, const float* __restrict__ Wq, const float* __restrict__ Wk,
    const float* __restrict__ qg, const float* __restrict__ qb, const float* __restrict__ qm,
    const float* __restrict__ qv, const float* __restrict__ kg, const float* __restrict__ kb,
    const float* __restrict__ km, const float* __restrict__ kv,
    __bf16* __restrict__ Qws, __bf16* __restrict__ Kws) {
  int b = blockIdx.z;
  int iblk = blockIdx.x, oblk = blockIdx.y;  // oblk 0..7: 0-3 -> Q, 4-7 -> K
  int wave = threadIdx.x >> 6, lane = threadIdx.x & 63;
  int g = lane >> 4, l16 = lane & 15;
  bool isQ = oblk < 4;
  const float* W = isQ ? Wq : Wk;
  int obase = (oblk & 3) * 64;
  int i0w = iblk * 64 + wave * 16;
  const __bf16* xrow = xT + ((size_t)b * NCTX + i0w + l16) * DIM;
  f32x4 acc[4] = {};
#pragma unroll
  for (int kc = 0; kc < 8; ++kc) {
    int c = kc * 32 + g * 8;
    bf16x8 a = *reinterpret_cast<const bf16x8*>(xrow + c);
#pragma unroll
    for (int ot = 0; ot < 4; ++ot) {
      const float* wrow = W + (size_t)(obase + ot * 16 + l16) * DIM + c;
      bf16x8 bf;
#pragma unroll
      for (int j = 0; j < 8; ++j) bf[j] = (__bf16)wrow[j];
      acc[ot] = __builtin_amdgcn_mfma_f32_16x16x32_bf16(a, bf, acc[ot], 0, 0, 0);
    }
  }
  const float* gam = isQ ? qg : kg;
  const float* bet = isQ ? qb : kb;
  const float* mea = isQ ? qm : km;
  const float* var = isQ ? qv : kv;
  float sfac = isQ ? SCALE : 1.0f;
  __bf16* OWS = isQ ? Qws : Kws;
#pragma unroll
  for (int ot = 0; ot < 4; ++ot) {
    int o = obase + ot * 16 + l16;
    float sclr = gam[o] * rsqrtf(var[o] + BN_EPS);
    float scl = sclr * sfac;
    float bia = (bet[o] - mea[o] * sclr) * sfac;
    int h = o >> 5, d = o & 31;
#pragma unroll
    for (int r = 0; r < 4; ++r) {
      int i = i0w + g * 4 + r;
      float v = acc[ot][r] * scl + bia;
      OWS[(((size_t)b * HEADS + h) * NCTX + i) * DK + d] = (__bf16)v;
    }
  }
}

// ---------------- V projection: A=Wv (M=o=512), B=xT (N=i), K=c=256 ----------------
// writes V natural [b, c=512, n] bf16, BN folded
__global__ __launch_bounds__(256) void k_proj_v(
    const __bf16* __restrict__ xT, const float* __restrict__ Wv,
    const float* __restrict__ vg, const float* __restrict__ vb, const float* __restrict__ vm,
    const float* __restrict__ vv, __bf16* __restrict__ Vws) {
  int b = blockIdx.z, oblk = blockIdx.x, iblk = blockIdx.y;
  int wave = threadIdx.x >> 6, lane = threadIdx.x & 63;
  int g = lane >> 4, l16 = lane & 15;
  int o0w = oblk * 64 + wave * 16;
  int ibase = iblk * 64;
  const float* wrow = Wv + (size_t)(o0w + l16) * DIM;
  f32x4 acc[4] = {};
#pragma unroll
  for (int kc = 0; kc < 8; ++kc) {
    int c = kc * 32 + g * 8;
    bf16x8 af;
#pragma unroll
    for (int j = 0; j < 8; ++j) af[j] = (__bf16)wrow[c + j];
#pragma unroll
    for (int it = 0; it < 4; ++it) {
      bf16x8 bf = *reinterpret_cast<const bf16x8*>(
          xT + ((size_t)b * NCTX + ibase + it * 16 + l16) * DIM + c);
      acc[it] = __builtin_amdgcn_mfma_f32_16x16x32_bf16(af, bf, acc[it], 0, 0, 0);
    }
  }
#pragma unroll
  for (int r = 0; r < 4; ++r) {
    int o = o0w + g * 4 + r;
    float sclr = vg[o] * rsqrtf(vv[o] + BN_EPS);
    float bia = vb[o] - vm[o] * sclr;
#pragma unroll
    for (int it = 0; it < 4; ++it) {
      int i = ibase + it * 16 + l16;
      Vws[((size_t)b * IDV + o) * NCTX + i] = (__bf16)(acc[it][r] * sclr + bia);
    }
  }
}

// ---------------- attention: flash-style, 1 block = (b,h) x 64 rows ----------------
__global__ __launch_bounds__(256) void k_attn(
    const __bf16* __restrict__ Qws, const __bf16* __restrict__ Kws,
    const __bf16* __restrict__ Vws, const float* __restrict__ pos_emb,
    __bf16* __restrict__ G) {
  int bh = blockIdx.y;
  int b = bh >> 3, h = bh & 7;
  int iblk = blockIdx.x;
  int wave = threadIdx.x >> 6, lane = threadIdx.x & 63;
  int g = lane >> 4, l16 = lane & 15;
  __shared__ float pe[NCTX];
  __shared__ __align__(16) __bf16 plds[4][16][40];
  for (int d = threadIdx.x; d < NCTX; d += 256) pe[d] = pos_emb[(size_t)d * HEADS + h] * INV_SCALE;
  __syncthreads();

  int i0w = iblk * 64 + wave * 16;
  const __bf16* qbase = Qws + (size_t)bh * NCTX * DK;
  const __bf16* kbase = Kws + (size_t)bh * NCTX * DK;
  const __bf16* vbase = Vws + ((size_t)b * IDV + h * DV) * NCTX;
  bf16x8 qfrag = *reinterpret_cast<const bf16x8*>(qbase + (size_t)(i0w + l16) * DK + g * 8);

  f32x4 acc[4] = {};
  float m[4], s[4];
  int irow[4];
#pragma unroll
  for (int r = 0; r < 4; ++r) { m[r] = -1e30f; s[r] = 0.0f; irow[r] = i0w + g * 4 + r; }

  for (int j0 = 0; j0 < NCTX; j0 += 32) {
    f32x4 S0, S1;
    {
      bf16x8 kf0 = *reinterpret_cast<const bf16x8*>(kbase + (size_t)(j0 + l16) * DK + g * 8);
      bf16x8 kf1 = *reinterpret_cast<const bf16x8*>(kbase + (size_t)(j0 + 16 + l16) * DK + g * 8);
      f32x4 z = {};
      S0 = __builtin_amdgcn_mfma_f32_16x16x32_bf16(qfrag, kf0, z, 0, 0, 0);
      S1 = __builtin_amdgcn_mfma_f32_16x16x32_bf16(qfrag, kf1, z, 0, 0, 0);
    }
    int jc0 = j0 + l16, jc1 = j0 + 16 + l16;
    float p0[4], p1[4];
#pragma unroll
    for (int r = 0; r < 4; ++r) {
      int d0 = irow[r] - jc0; d0 = d0 < 0 ? -d0 : d0;
      int d1 = irow[r] - jc1; d1 = d1 < 0 ? -d1 : d1;
      float s0 = S0[r] + pe[d0];
      float s1 = S1[r] + pe[d1];
      float mx = fmaxf(s0, s1);
      mx = fmaxf(mx, __shfl_xor(mx, 1));
      mx = fmaxf(mx, __shfl_xor(mx, 2));
      mx = fmaxf(mx, __shfl_xor(mx, 4));
      mx = fmaxf(mx, __shfl_xor(mx, 8));
      float mnew = fmaxf(m[r], mx);
      float corr = __expf(m[r] - mnew);
      float e0 = __expf(s0 - mnew);
      float e1 = __expf(s1 - mnew);
      float ps = e0 + e1;
      ps += __shfl_xor(ps, 1);
      ps += __shfl_xor(ps, 2);
      ps += __shfl_xor(ps, 4);
      ps += __shfl_xor(ps, 8);
      s[r] = s[r] * corr + ps;
      m[r] = mnew;
      acc[0][r] *= corr; acc[1][r] *= corr; acc[2][r] *= corr; acc[3][r] *= corr;
      p0[r] = e0; p1[r] = e1;
    }
    // P (D-layout) -> LDS -> A-layout fragment
    __builtin_amdgcn_sched_barrier(0);
#pragma unroll
    for (int r = 0; r < 4; ++r) {
      plds[wave][g * 4 + r][l16] = (__bf16)p0[r];
      plds[wave][g * 4 + r][16 + l16] = (__bf16)p1[r];
    }
    __builtin_amdgcn_sched_barrier(0);
    bf16x8 pfrag = *reinterpret_cast<const bf16x8*>(&plds[wave][l16][g * 8]);
    __builtin_amdgcn_sched_barrier(0);
#pragma unroll
    for (int dt = 0; dt < 4; ++dt) {
      bf16x8 vf = *reinterpret_cast<const bf16x8*>(
          vbase + (size_t)(dt * 16 + l16) * NCTX + j0 + g * 8);
      acc[dt] = __builtin_amdgcn_mfma_f32_16x16x32_bf16(pfrag, vf, acc[dt], 0, 0, 0);
    }
  }
  // epilogue: /s, gelu(exact), write G[b,n,c] bf16
  float inv[4];
#pragma unroll
  for (int r = 0; r < 4; ++r) inv[r] = 1.0f / s[r];
  __bf16* gbase = G + (size_t)b * NCTX * IDV;
#pragma unroll
  for (int dt = 0; dt < 4; ++dt) {
    int cch = h * DV + dt * 16 + l16;
#pragma unroll
    for (int r = 0; r < 4; ++r) {
      float v = acc[dt][r] * inv[r];
      float ge = 0.5f * v * (1.0f + erff(v * 0.70710678118654752f));
      gbase[(size_t)irow[r] * IDV + cch] = (__bf16)ge;
    }
  }
}

// ---------------- out projection: A=Wo (M=o=256), B=G (N=i), K=c=512 ----------------
__global__ __launch_bounds__(256) void k_out(
    const __bf16* __restrict__ G, const float* __restrict__ Wo, const float* __restrict__ bo,
    const float* __restrict__ og, const float* __restrict__ ob, const float* __restrict__ om,
    const float* __restrict__ ov, float* __restrict__ out) {
  int b = blockIdx.z, oblk = blockIdx.x, iblk = blockIdx.y;
  int wave = threadIdx.x >> 6, lane = threadIdx.x & 63;
  int g = lane >> 4, l16 = lane & 15;
  int o0w = oblk * 64 + wave * 16;
  int ibase = iblk * 64;
  const float* wrow = Wo + (size_t)(o0w + l16) * IDV;
  const __bf16* gb = G + (size_t)b * NCTX * IDV;
  f32x4 acc[4] = {};
#pragma unroll
  for (int kc = 0; kc < 16; ++kc) {
    int c = kc * 32 + g * 8;
    bf16x8 af;
#pragma unroll
    for (int j = 0; j < 8; ++j) af[j] = (__bf16)wrow[c + j];
#pragma unroll
    for (int it = 0; it < 4; ++it) {
      bf16x8 bf = *reinterpret_cast<const bf16x8*>(
          gb + (size_t)(ibase + it * 16 + l16) * IDV + c);
      acc[it] = __builtin_amdgcn_mfma_f32_16x16x32_bf16(af, bf, acc[it], 0, 0, 0);
    }
  }
#pragma unroll
  for (int r = 0; r < 4; ++r) {
    int o = o0w + g * 4 + r;
    float sclr = og[o] * rsqrtf(ov[o] + BN_EPS);
    float bia = (bo[o] - om[o]) * sclr + ob[o];
#pragma unroll
    for (int it = 0; it < 4; ++it) {
      int i = ibase + it * 16 + l16;
      out[((size_t)b * DIM + o) * NCTX + i] = acc[it][r] * sclr + bia;
    }
  }
}

extern "C" void kernel_launch(void* const* d_in, const int* in_sizes, int n_in,
                              void* d_out, int out_size, void* d_ws, size_t ws_size,
                              hipStream_t stream) {
  const float* x  = (const float*)d_in[0];
  const float* Wq = (const float*)d_in[1];
  const float* Wk = (const float*)d_in[2];
  const float* Wv = (const float*)d_in[3];
  const float* Wo = (const float*)d_in[4];
  const float* bo = (const float*)d_in[5];
  const float* pe = (const float*)d_in[6];
  const float* qg = (const float*)d_in[7];
  const float* qb = (const float*)d_in[8];
  const float* qm = (const float*)d_in[9];
  const float* qv = (const float*)d_in[10];
  const float* kg = (const float*)d_in[11];
  const float* kb = (const float*)d_in[12];
  const float* km = (const float*)d_in[13];
  const float* kv = (const float*)d_in[14];
  const float* vg = (const float*)d_in[15];
  const float* vb = (const float*)d_in[16];
  const float* vm = (const float*)d_in[17];
  const float* vv = (const float*)d_in[18];
  const float* og = (const float*)d_in[19];
  const float* ob = (const float*)d_in[20];
  const float* om = (const float*)d_in[21];
  const float* ov = (const float*)d_in[22];

  char* ws = (char*)d_ws;
  __bf16* xT = (__bf16*)(ws);                       // 4 MB
  __bf16* Q  = (__bf16*)(ws + (4ull << 20));        // 4 MB
  __bf16* K  = (__bf16*)(ws + (8ull << 20));        // 4 MB
  __bf16* V  = (__bf16*)(ws + (12ull << 20));       // 8 MB
  __bf16* G  = (__bf16*)(ws + (20ull << 20));       // 8 MB
  float* out = (float*)d_out;

  k_transpose<<<dim3(16, 4, NB), 256, 0, stream>>>(x, xT);
  k_proj_qk<<<dim3(16, 8, NB), 256, 0, stream>>>(xT, Wq, Wk, qg, qb, qm, qv,
                                                 kg, kb, km, kv, Q, K);
  k_proj_v<<<dim3(8, 16, NB), 256, 0, stream>>>(xT, Wv, vg, vb, vm, vv, V);
  k_attn<<<dim3(16, 64), 256, 0, stream>>>(Q, K, V, pe, G);
  k_out<<<dim3(4, 16, NB), 256, 0, stream>>>(G, Wo, bo, og, ob, om, ov, out);
}

// Round 2
// 170.746 us; speedup vs baseline: 1.0148x; 1.0148x over previous
//
#include <hip/hip_runtime.h>
#include <hip/hip_bf16.h>

#define HEADS 8
#define DK 32
#define DV 64
#define DIM 256
#define NCTX 1024
#define NB 8
#define IDK 256
#define IDV 512
#define SCALE 0.17677669529663687f
#define INV_SCALE 5.656854249492381f
#define BN_EPS 1e-5f
#define THR 8.0f

typedef __bf16 bf16x8 __attribute__((ext_vector_type(8)));
typedef __bf16 bf16x4 __attribute__((ext_vector_type(4)));
typedef float f32x4 __attribute__((ext_vector_type(4)));

// ---------------- transpose x[b,c,n] f32 -> xT[b,n,c] bf16 ----------------
__global__ __launch_bounds__(256) void k_transpose(const float* __restrict__ x,
                                                   __bf16* __restrict__ xT) {
  __shared__ float t[64][65];
  int b = blockIdx.z, c0 = blockIdx.y * 64, n0 = blockIdx.x * 64;
  int col = threadIdx.x & 63, rb = threadIdx.x >> 6;
  const float* xp = x + ((size_t)b * DIM + c0) * NCTX + n0;
#pragma unroll
  for (int r = 0; r < 16; ++r) {
    int row = rb + 4 * r;
    t[row][col] = xp[(size_t)row * NCTX + col];
  }
  __syncthreads();
  __bf16* op = xT + ((size_t)b * NCTX + n0) * DIM + c0;
#pragma unroll
  for (int r = 0; r < 16; ++r) {
    int i = rb + 4 * r;
    op[(size_t)i * DIM + col] = (__bf16)t[col][i];
  }
}

// ---------------- Q/K projection: A=xT (M=i), B=W (N=o), K=c=256 ----------------
__global__ __launch_bounds__(256) void k_proj_qk(
    const __bf16* __restrict__ xT, const float* __restrict__ Wq, const float* __restrict__ Wk,
    const float* __restrict__ qg, const float* __restrict__ qb, const float* __restrict__ qm,
    const float* __restrict__ qv, const float* __restrict__ kg, const float* __restrict__ kb,
    const float* __restrict__ km, const float* __restrict__ kv,
    __bf16* __restrict__ Qws, __bf16* __restrict__ Kws) {
  int b = blockIdx.z;
  int iblk = blockIdx.x, oblk = blockIdx.y;  // oblk 0..7: 0-3 -> Q, 4-7 -> K
  int wave = threadIdx.x >> 6, lane = threadIdx.x & 63;
  int g = lane >> 4, l16 = lane & 15;
  bool isQ = oblk < 4;
  const float* W = isQ ? Wq : Wk;
  int obase = (oblk & 3) * 64;
  int i0w = iblk * 64 + wave * 16;
  const __bf16* xrow = xT + ((size_t)b * NCTX + i0w + l16) * DIM;
  f32x4 acc[4] = {};
#pragma unroll
  for (int kc = 0; kc < 8; ++kc) {
    int c = kc * 32 + g * 8;
    bf16x8 a = *reinterpret_cast<const bf16x8*>(xrow + c);
#pragma unroll
    for (int ot = 0; ot < 4; ++ot) {
      const float* wrow = W + (size_t)(obase + ot * 16 + l16) * DIM + c;
      bf16x8 bf;
#pragma unroll
      for (int j = 0; j < 8; ++j) bf[j] = (__bf16)wrow[j];
      acc[ot] = __builtin_amdgcn_mfma_f32_16x16x32_bf16(a, bf, acc[ot], 0, 0, 0);
    }
  }
  const float* gam = isQ ? qg : kg;
  const float* bet = isQ ? qb : kb;
  const float* mea = isQ ? qm : km;
  const float* var = isQ ? qv : kv;
  float sfac = isQ ? SCALE : 1.0f;
  __bf16* OWS = isQ ? Qws : Kws;
#pragma unroll
  for (int ot = 0; ot < 4; ++ot) {
    int o = obase + ot * 16 + l16;
    float sclr = gam[o] * rsqrtf(var[o] + BN_EPS);
    float scl = sclr * sfac;
    float bia = (bet[o] - mea[o] * sclr) * sfac;
    int h = o >> 5, d = o & 31;
#pragma unroll
    for (int r = 0; r < 4; ++r) {
      int i = i0w + g * 4 + r;
      float v = acc[ot][r] * scl + bia;
      OWS[(((size_t)b * HEADS + h) * NCTX + i) * DK + d] = (__bf16)v;
    }
  }
}

// ---------------- V projection: A=Wv (M=o=512), B=xT (N=i), K=c=256 ----------------
__global__ __launch_bounds__(256) void k_proj_v(
    const __bf16* __restrict__ xT, const float* __restrict__ Wv,
    const float* __restrict__ vg, const float* __restrict__ vb, const float* __restrict__ vm,
    const float* __restrict__ vv, __bf16* __restrict__ Vws) {
  int b = blockIdx.z, oblk = blockIdx.x, iblk = blockIdx.y;
  int wave = threadIdx.x >> 6, lane = threadIdx.x & 63;
  int g = lane >> 4, l16 = lane & 15;
  int o0w = oblk * 64 + wave * 16;
  int ibase = iblk * 64;
  const float* wrow = Wv + (size_t)(o0w + l16) * DIM;
  f32x4 acc[4] = {};
#pragma unroll
  for (int kc = 0; kc < 8; ++kc) {
    int c = kc * 32 + g * 8;
    bf16x8 af;
#pragma unroll
    for (int j = 0; j < 8; ++j) af[j] = (__bf16)wrow[c + j];
#pragma unroll
    for (int it = 0; it < 4; ++it) {
      bf16x8 bf = *reinterpret_cast<const bf16x8*>(
          xT + ((size_t)b * NCTX + ibase + it * 16 + l16) * DIM + c);
      acc[it] = __builtin_amdgcn_mfma_f32_16x16x32_bf16(af, bf, acc[it], 0, 0, 0);
    }
  }
#pragma unroll
  for (int r = 0; r < 4; ++r) {
    int o = o0w + g * 4 + r;
    float sclr = vg[o] * rsqrtf(vv[o] + BN_EPS);
    float bia = vb[o] - vm[o] * sclr;
#pragma unroll
    for (int it = 0; it < 4; ++it) {
      int i = ibase + it * 16 + l16;
      Vws[((size_t)b * IDV + o) * NCTX + i] = (__bf16)(acc[it][r] * sclr + bia);
    }
  }
}

// ---------------- attention: flash-style, swapped QK^T + defer-max ----------------
// 1 block = (b,h) x 64 rows; wave owns 16 rows. Lane owns ONE q-row (i = l16);
// per 32-j chunk lane holds 8 S-values -> softmax is lane-local except rare
// rescale events (defer-max, THR=8) and the single epilogue sum-tree.
__global__ __launch_bounds__(256) void k_attn(
    const __bf16* __restrict__ Qws, const __bf16* __restrict__ Kws,
    const __bf16* __restrict__ Vws, const float* __restrict__ pos_emb,
    __bf16* __restrict__ G) {
  int bh = blockIdx.y;
  int b = bh >> 3, h = bh & 7;
  int iblk = blockIdx.x;
  int wave = threadIdx.x >> 6, lane = threadIdx.x & 63;
  int g = lane >> 4, l16 = lane & 15;
  int g4 = g * 4;
  __shared__ float pe[NCTX];
  __shared__ __align__(16) __bf16 plds[4][16][40];
  for (int d = threadIdx.x; d < NCTX; d += 256) pe[d] = pos_emb[(size_t)d * HEADS + h] * INV_SCALE;
  __syncthreads();

  int i0w = iblk * 64 + wave * 16;
  int irow = i0w + l16;  // this lane's q-row
  const __bf16* qbase = Qws + (size_t)bh * NCTX * DK;
  const __bf16* kbase = Kws + (size_t)bh * NCTX * DK;
  const __bf16* vbase = Vws + ((size_t)b * IDV + h * DV) * NCTX;
  // Q fragment (B-operand of swapped S-MFMA): lane holds Q[i=l16][d=g*8..+8]
  bf16x8 qfrag = *reinterpret_cast<const bf16x8*>(qbase + (size_t)(i0w + l16) * DK + g * 8);

  f32x4 acc[4] = {};
  float m = -1e30f, s = 0.0f;

  for (int j0 = 0; j0 < NCTX; j0 += 32) {
    f32x4 S0, S1;
    {
      // K fragments (A-operand): lane holds K[j=j0(+16)+l16][d=g*8..+8]
      bf16x8 kf0 = *reinterpret_cast<const bf16x8*>(kbase + (size_t)(j0 + l16) * DK + g * 8);
      bf16x8 kf1 = *reinterpret_cast<const bf16x8*>(kbase + (size_t)(j0 + 16 + l16) * DK + g * 8);
      f32x4 z = {};
      S0 = __builtin_amdgcn_mfma_f32_16x16x32_bf16(kf0, qfrag, z, 0, 0, 0);  // S^T tile0
      S1 = __builtin_amdgcn_mfma_f32_16x16x32_bf16(kf1, qfrag, z, 0, 0, 0);  // S^T tile1
    }
    // lane's 8 scores: j = j0 + g4 + r  and  j0 + 16 + g4 + r, all at row irow
    float sv[8];
#pragma unroll
    for (int r = 0; r < 4; ++r) {
      int jl0 = j0 + g4 + r;
      int jl1 = jl0 + 16;
      int d0 = irow - jl0; d0 = d0 < 0 ? -d0 : d0;
      int d1 = irow - jl1; d1 = d1 < 0 ? -d1 : d1;
      sv[r] = S0[r] + pe[d0];
      sv[r + 4] = S1[r] + pe[d1];
    }
    float pmax = sv[0];
#pragma unroll
    for (int k = 1; k < 8; ++k) pmax = fmaxf(pmax, sv[k]);
    if (__any(pmax > m + THR)) {  // rare: first chunk + genuine max growth
      float mx = fmaxf(pmax, __shfl_xor(pmax, 16));
      mx = fmaxf(mx, __shfl_xor(mx, 32));
      float mnew = fmaxf(m, mx);
      float corr = __expf(m - mnew);
      s *= corr;
      m = mnew;
#pragma unroll
      for (int r = 0; r < 4; ++r) {
        float c = __shfl(corr, (lane & 48) | (g4 + r));
        acc[0][r] *= c; acc[1][r] *= c; acc[2][r] *= c; acc[3][r] *= c;
      }
    }
    float e[8];
#pragma unroll
    for (int k = 0; k < 8; ++k) e[k] = __expf(sv[k] - m);
    s += ((e[0] + e[1]) + (e[2] + e[3])) + ((e[4] + e[5]) + (e[6] + e[7]));
    // P -> LDS: lane writes its own row, 2x packed b64
    bf16x4 pk0, pk1;
#pragma unroll
    for (int r = 0; r < 4; ++r) { pk0[r] = (__bf16)e[r]; pk1[r] = (__bf16)e[r + 4]; }
    *reinterpret_cast<bf16x4*>(&plds[wave][l16][g4]) = pk0;
    *reinterpret_cast<bf16x4*>(&plds[wave][l16][16 + g4]) = pk1;
    // A-fragment for PV: lane reads P[i=l16][j-local g*8..+8]
    bf16x8 pfrag = *reinterpret_cast<const bf16x8*>(&plds[wave][l16][g * 8]);
#pragma unroll
    for (int dt = 0; dt < 4; ++dt) {
      bf16x8 vf = *reinterpret_cast<const bf16x8*>(
          vbase + (size_t)(dt * 16 + l16) * NCTX + j0 + g * 8);
      acc[dt] = __builtin_amdgcn_mfma_f32_16x16x32_bf16(pfrag, vf, acc[dt], 0, 0, 0);
    }
  }
  // epilogue: single sum-tree across the row's 4 g-lanes, then /s, gelu, store
  s += __shfl_xor(s, 16);
  s += __shfl_xor(s, 32);
  float inv = 1.0f / s;  // valid for row irow (= l16 slot)
  float invr[4];
#pragma unroll
  for (int r = 0; r < 4; ++r) invr[r] = __shfl(inv, (lane & 48) | (g4 + r));
  __bf16* gbase = G + (size_t)b * NCTX * IDV;
#pragma unroll
  for (int dt = 0; dt < 4; ++dt) {
    int cch = h * DV + dt * 16 + l16;
#pragma unroll
    for (int r = 0; r < 4; ++r) {
      float v = acc[dt][r] * invr[r];
      float ge = 0.5f * v * (1.0f + erff(v * 0.70710678118654752f));
      gbase[(size_t)(i0w + g4 + r) * IDV + cch] = (__bf16)ge;
    }
  }
}

// ---------------- out projection: A=Wo (M=o=256), B=G (N=i), K=c=512 ----------------
__global__ __launch_bounds__(256) void k_out(
    const __bf16* __restrict__ G, const float* __restrict__ Wo, const float* __restrict__ bo,
    const float* __restrict__ og, const float* __restrict__ ob, const float* __restrict__ om,
    const float* __restrict__ ov, float* __restrict__ out) {
  int b = blockIdx.z, oblk = blockIdx.x, iblk = blockIdx.y;
  int wave = threadIdx.x >> 6, lane = threadIdx.x & 63;
  int g = lane >> 4, l16 = lane & 15;
  int o0w = oblk * 64 + wave * 16;
  int ibase = iblk * 64;
  const float* wrow = Wo + (size_t)(o0w + l16) * IDV;
  const __bf16* gb = G + (size_t)b * NCTX * IDV;
  f32x4 acc[4] = {};
#pragma unroll
  for (int kc = 0; kc < 16; ++kc) {
    int c = kc * 32 + g * 8;
    bf16x8 af;
#pragma unroll
    for (int j = 0; j < 8; ++j) af[j] = (__bf16)wrow[c + j];
#pragma unroll
    for (int it = 0; it < 4; ++it) {
      bf16x8 bf = *reinterpret_cast<const bf16x8*>(
          gb + (size_t)(ibase + it * 16 + l16) * IDV + c);
      acc[it] = __builtin_amdgcn_mfma_f32_16x16x32_bf16(af, bf, acc[it], 0, 0, 0);
    }
  }
#pragma unroll
  for (int r = 0; r < 4; ++r) {
    int o = o0w + g * 4 + r;
    float sclr = og[o] * rsqrtf(ov[o] + BN_EPS);
    float bia = (bo[o] - om[o]) * sclr + ob[o];
#pragma unroll
    for (int it = 0; it < 4; ++it) {
      int i = ibase + it * 16 + l16;
      out[((size_t)b * DIM + o) * NCTX + i] = acc[it][r] * sclr + bia;
    }
  }
}

extern "C" void kernel_launch(void* const* d_in, const int* in_sizes, int n_in,
                              void* d_out, int out_size, void* d_ws, size_t ws_size,
                              hipStream_t stream) {
  const float* x  = (const float*)d_in[0];
  const float* Wq = (const float*)d_in[1];
  const float* Wk = (const float*)d_in[2];
  const float* Wv = (const float*)d_in[3];
  const float* Wo = (const float*)d_in[4];
  const float* bo = (const float*)d_in[5];
  const float* pe = (const float*)d_in[6];
  const float* qg = (const float*)d_in[7];
  const float* qb = (const float*)d_in[8];
  const float* qm = (const float*)d_in[9];
  const float* qv = (const float*)d_in[10];
  const float* kg = (const float*)d_in[11];
  const float* kb = (const float*)d_in[12];
  const float* km = (const float*)d_in[13];
  const float* kv = (const float*)d_in[14];
  const float* vg = (const float*)d_in[15];
  const float* vb = (const float*)d_in[16];
  const float* vm = (const float*)d_in[17];
  const float* vv = (const float*)d_in[18];
  const float* og = (const float*)d_in[19];
  const float* ob = (const float*)d_in[20];
  const float* om = (const float*)d_in[21];
  const float* ov = (const float*)d_in[22];

  char* ws = (char*)d_ws;
  __bf16* xT = (__bf16*)(ws);                       // 4 MB
  __bf16* Q  = (__bf16*)(ws + (4ull << 20));        // 4 MB
  __bf16* K  = (__bf16*)(ws + (8ull << 20));        // 4 MB
  __bf16* V  = (__bf16*)(ws + (12ull << 20));       // 8 MB
  __bf16* G  = (__bf16*)(ws + (20ull << 20));       // 8 MB
  float* out = (float*)d_out;

  k_transpose<<<dim3(16, 4, NB), 256, 0, stream>>>(x, xT);
  k_proj_qk<<<dim3(16, 8, NB), 256, 0, stream>>>(xT, Wq, Wk, qg, qb, qm, qv,
                                                 kg, kb, km, kv, Q, K);
  k_proj_v<<<dim3(8, 16, NB), 256, 0, stream>>>(xT, Wv, vg, vb, vm, vv, V);
  k_attn<<<dim3(16, 64), 256, 0, stream>>>(Q, K, V, pe, G);
  k_out<<<dim3(4, 16, NB), 256, 0, stream>>>(G, Wo, bo, og, ob, om, ov, out);
}